// Round 6
// baseline (90.297 us; speedup 1.0000x reference)
//
#include <hip/hip_runtime.h>
#include <stdint.h>

// ---------------------------------------------------------------------------
// GSDepthRankingLoss on MI355X — R5:
//   - atomic-free segmented worklist (bcount[] per block, no global counter)
//   - PRNG ILP fence (8 independent threefry chains live at once)
//   - bf16 crop table (4.15MB, XCD-L2 resident), ONE aligned dwordx4 per row
// JAX threefry (partitionable) verified bit-exact R0-R4 (absmax 0).
// ---------------------------------------------------------------------------

#define IMG_W 1920
#define IMG_H 1080
#define N_PIX (IMG_W * IMG_H)
#define N_SAMP 518400          // int(1920*1080*0.25) == 2025 * 256
#define SEG    2025            // worklist segments (one per sample block)
#define PAD_VAL (-1000000.0f)

struct Keys { uint32_t k[5][2][2]; };  // [randint id][k1|k2][key word]

// Threefry-2x32, 20 rounds (Random123 / JAX-compatible).
static __host__ __device__ inline void tf2x32(uint32_t k0, uint32_t k1,
                                              uint32_t x0, uint32_t x1,
                                              uint32_t& o0, uint32_t& o1)
{
  const uint32_t ks2 = k0 ^ k1 ^ 0x1BD11BDAu;
  x0 += k0; x1 += k1;
#define TFR(r) { x0 += x1; x1 = (x1 << (r)) | (x1 >> (32 - (r))); x1 ^= x0; }
  TFR(13) TFR(15) TFR(26) TFR(6)
  x0 += k1;  x1 += ks2 + 1u;
  TFR(17) TFR(29) TFR(16) TFR(24)
  x0 += ks2; x1 += k0 + 2u;
  TFR(13) TFR(15) TFR(26) TFR(6)
  x0 += k0;  x1 += k1 + 3u;
  TFR(17) TFR(29) TFR(16) TFR(24)
  x0 += k1;  x1 += ks2 + 4u;
  TFR(13) TFR(15) TFR(26) TFR(6)
  x0 += ks2; x1 += k0 + 5u;
#undef TFR
  o0 = x0; o1 = x1;
}

__device__ __forceinline__ uint32_t jrbits(const uint32_t kk[2], uint32_t f)
{
  uint32_t a, b;
  tf2x32(kk[0], kk[1], 0u, f, a, b);   // partitionable: counts = (0, f)
  return a ^ b;                        // 32-bit fold
}

__device__ __forceinline__ uint32_t jrandint(const Keys& K, int r, uint32_t f,
                                             uint32_t span)
{
  const uint32_t hi = jrbits(K.k[r][0], f);
  const uint32_t lo = jrbits(K.k[r][1], f);
  uint32_t m = 65536u % span;
  m = (m * m) % span;
  return ((hi % span) * m + (lo % span)) % span;
}

static void compute_keys(Keys& K)
{
  uint32_t ks[5][2];
  for (uint32_t t = 0; t < 5; t++) {
    uint32_t a, b; tf2x32(0u, 42u, 0u, t, a, b);   // split of key(42)
    ks[t][0] = a; ks[t][1] = b;
  }
  for (int r = 0; r < 5; r++) {                    // randint's internal _split
    uint32_t a, b;
    tf2x32(ks[r][0], ks[r][1], 0u, 0u, a, b); K.k[r][0][0] = a; K.k[r][0][1] = b;
    tf2x32(ks[r][0], ks[r][1], 0u, 1u, a, b); K.k[r][1][0] = a; K.k[r][1][1] = b;
  }
}

__device__ __forceinline__ bool bittest(const unsigned long long* __restrict__ vb,
                                        uint32_t idx)
{
  return ((vb[idx >> 6] >> (idx & 63u)) & 1ull) != 0ull;
}

// ---------------- K1: bitpack valid mask (2073600 ints -> 259KB) ------------
__global__ __launch_bounds__(256) void gs_bitpack(
    const int* __restrict__ vmask,
    unsigned long long* __restrict__ vbits)
{
  const uint32_t gid = blockIdx.x * 256u + threadIdx.x;   // 8100*256 == N_PIX
  const unsigned long long ball = __ballot(vmask[gid] != 0);
  if ((threadIdx.x & 63u) == 0) vbits[gid >> 6] = ball;
}

// ---------------- K1b: bf16 (truncated) copy of target depths ---------------
__global__ __launch_bounds__(256) void gs_pack16(
    const float* __restrict__ tgt,
    uint32_t* __restrict__ tgt16)   // 2 bf16 per word
{
  const uint32_t gid = blockIdx.x * 256u + threadIdx.x;
  if (gid >= (uint32_t)(N_PIX / 8)) return;
  const uint32_t* s = (const uint32_t*)tgt + gid * 8u;
  uint32_t w[4];
#pragma unroll
  for (int i = 0; i < 4; i++)
    w[i] = (s[2 * i] >> 16) | (s[2 * i + 1] & 0xFFFF0000u);
  uint32_t* d = tgt16 + gid * 4u;
  __builtin_memcpy(d, w, 16);
}

// ---------------- K2: PRNG + mask -> segmented worklist (NO atomics) --------
// Entry (64b): [nbr1:4 @48][nbr0:4 @44][sy0:11 @33][sx0:11 @22][sy1:11 @11][sx1:11 @0]
__global__ __launch_bounds__(256) void gs_sample(
    const unsigned long long* __restrict__ vbits,
    uint32_t* __restrict__ bcount,
    unsigned long long* __restrict__ wlist,
    Keys K)
{
  __shared__ unsigned long long ent[256];
  __shared__ uint32_t scnt[4];

  const uint32_t tid  = threadIdx.x;
  const uint32_t lane = tid & 63u;
  const uint32_t wave = tid >> 6;
  const uint32_t ui   = blockIdx.x * 256u + tid;   // grid covers N_SAMP exactly

  // 8 independent randint chains; fence forces simultaneous liveness -> ILP.
  const uint32_t syb  = jrandint(K, 0, ui, 840u);    // H - 240
  const uint32_t sxb  = jrandint(K, 1, ui, 1680u);   // W - 240
  const uint32_t oy0  = jrandint(K, 2, 2u * ui,      240u);
  const uint32_t oy1  = jrandint(K, 2, 2u * ui + 1u, 240u);
  const uint32_t ox0  = jrandint(K, 3, 2u * ui,      240u);
  const uint32_t ox1  = jrandint(K, 3, 2u * ui + 1u, 240u);
  const uint32_t nb0  = jrandint(K, 4, 2u * ui,      14u);
  const uint32_t nb1  = jrandint(K, 4, 2u * ui + 1u, 14u);
  asm volatile("" :: "v"(syb), "v"(sxb), "v"(oy0), "v"(oy1),
                     "v"(ox0), "v"(ox1), "v"(nb0), "v"(nb1));

  const uint32_t sy0 = syb + oy0, sy1 = syb + oy1;
  const uint32_t sx0 = sxb + ox0, sx1 = sxb + ox1;
  const bool ok = bittest(vbits, sy0 * IMG_W + sx0) &&
                  bittest(vbits, sy1 * IMG_W + sx1);

  const unsigned long long ball = __ballot(ok);
  if (lane == 0) scnt[wave] = (uint32_t)__popcll(ball);
  __syncthreads();

  uint32_t base = 0;
#pragma unroll
  for (uint32_t w = 0; w < 4; w++) if (w < wave) base += scnt[w];
  const uint32_t nsurv = scnt[0] + scnt[1] + scnt[2] + scnt[3];

  if (ok) {
    const uint32_t pos = base + (uint32_t)__popcll(ball & ((1ull << lane) - 1ull));
    ent[pos] = ((unsigned long long)(1u + nb1) << 48) |
               ((unsigned long long)(1u + nb0) << 44) |
               ((unsigned long long)sy0 << 33) | ((unsigned long long)sx0 << 22) |
               ((unsigned long long)sy1 << 11) |  (unsigned long long)sx1;
  }
  if (tid == 0) bcount[blockIdx.x] = nsurv;
  __syncthreads();

  const unsigned long long* eb = ent;
  unsigned long long* wb = wlist + (size_t)blockIdx.x * 256u;
  for (uint32_t t = tid; t < nsurv; t += 256u)
    wb[t] = eb[t];                      // coalesced, segment-local
}

// nbr-th nearest neighbour from the bf16 crop table. ONE aligned dwordx4
// per row (8 ushorts at even base), 7 rows held live before the sort.
__device__ __forceinline__ int crop_neighbor16(
    const uint32_t* __restrict__ tgt16,   // word i = pixels (2i, 2i+1)
    int sy, int sx, float sd, uint32_t nbr)
{
  const int x0 = sx - 3;                 // leftmost crop col
  const int ex = x0 & ~1;                // even load base
  const uint32_t s = (uint32_t)(x0 & 1); // 0 or 1 shift into loaded 8
  float vals[7][8];

  const bool interior = (sy >= 3) && (sy <= IMG_H - 4) &&
                        (ex >= 0) && (ex <= IMG_W - 8);
  if (interior) {
    uint32_t R[7][4];
    const uint32_t* p = tgt16 + ((sy - 3) * IMG_W + ex) / 2;
#pragma unroll
    for (int r = 0; r < 7; r++) {
      R[r][0] = p[r * (IMG_W / 2) + 0];
      R[r][1] = p[r * (IMG_W / 2) + 1];
      R[r][2] = p[r * (IMG_W / 2) + 2];
      R[r][3] = p[r * (IMG_W / 2) + 3];
    }
    __builtin_amdgcn_sched_barrier(0);   // all 28 words in flight first
#pragma unroll
    for (int r = 0; r < 7; r++)
#pragma unroll
      for (int k = 0; k < 8; k++) {
        const uint32_t wrd = R[r][k >> 1];
        vals[r][k] = __uint_as_float((k & 1) ? (wrd & 0xFFFF0000u)
                                             : (wrd << 16));
      }
  } else {
    // rare edge path: guarded scalar bf16 loads, PAD semantics
    const unsigned short* t16 = (const unsigned short*)tgt16;
#pragma unroll
    for (int r = 0; r < 7; r++) {
      const int yy = sy - 3 + r;
      const bool rok = (yy >= 0) && (yy < IMG_H);
#pragma unroll
      for (int k = 0; k < 8; k++) {
        const int xx = ex + k;
        const bool okc = rok && (xx >= 0) && (xx < IMG_W);
        vals[r][k] = okc
            ? __uint_as_float((uint32_t)t16[yy * IMG_W + xx] << 16)
            : PAD_VAL;
      }
    }
  }

  // 15 smallest of 49 keys: (|v-sd|bits & ~63) | pos; stable ties by pos.
  uint32_t arr[15];
#pragma unroll
  for (int t = 0; t < 15; t++) arr[t] = 0xFFFFFFFFu;

#pragma unroll
  for (int r = 0; r < 7; r++) {
#pragma unroll
    for (int c = 0; c < 7; c++) {
      const float v = s ? vals[r][c + 1] : vals[r][c];   // runtime shift select
      const int q = r * 7 + c;
      uint32_t key = (__float_as_uint(v - sd) & 0x7FFFFFC0u) | (uint32_t)q;
      const int depth = (q + 1 < 15) ? (q + 1) : 15;     // triangular insert
#pragma unroll
      for (int t = 0; t < 15; t++) {
        if (t < depth) {
          const uint32_t lo = min(key, arr[t]);
          const uint32_t hi = max(key, arr[t]);
          arr[t] = lo; key = hi;
        }
      }
    }
  }

  uint32_t relkey = 0;
#pragma unroll
  for (int t = 1; t < 15; t++)
    if ((uint32_t)t == nbr) relkey = arr[t];
  const uint32_t rel = relkey & 63u;
  return (sy - 3 + (int)(rel / 7u)) * IMG_W + (sx - 3 + (int)(rel % 7u));
}

// ---------------- K3: crops on segment pairs (dense, no atomic handoff) -----
__global__ __launch_bounds__(256, 6) void gs_crop(
    const uint32_t* __restrict__ tgt16,
    const float* __restrict__ rnd,
    const unsigned long long* __restrict__ vbits,
    const uint32_t* __restrict__ bcount,
    const unsigned long long* __restrict__ wlist,
    float* __restrict__ acc)
{
  __shared__ float partial[12];
  const uint32_t tid  = threadIdx.x;
  const uint32_t lane = tid & 63u;
  const uint32_t wave = tid >> 6;

  const uint32_t seg0 = 2u * blockIdx.x;
  const uint32_t c0 = bcount[seg0];
  const uint32_t c1 = (seg0 + 1 < SEG) ? bcount[seg0 + 1] : 0;
  const uint32_t m  = 2u * (c0 + c1);            // crops this block (even)
  const unsigned short* t16s = (const unsigned short*)tgt16;

  float rank_a = 0.f, cont_a = 0.f, cnt_a = 0.f;
  for (uint32_t t = tid; t < ((m + 255u) & ~255u); t += 256u) {
    float sd = 0.f, r = 0.f, q = 0.f;
    bool v = false;
    if (t < m) {
      const uint32_t tc0 = 2u * c0;
      const unsigned long long e = (t < tc0)
          ? wlist[(size_t)seg0 * 256u + (t >> 1)]
          : wlist[(size_t)(seg0 + 1) * 256u + ((t - tc0) >> 1)];
      const int j = (int)(t & 1u);               // tc0 even -> parity safe
      const int sy  = j ? (int)((e >> 11) & 2047u) : (int)((e >> 33) & 2047u);
      const int sx  = j ? (int)( e        & 2047u) : (int)((e >> 22) & 2047u);
      const uint32_t nbr = j ? (uint32_t)((e >> 48) & 15u)
                             : (uint32_t)((e >> 44) & 15u);
      const int sidx = sy * IMG_W + sx;
      sd = __uint_as_float((uint32_t)t16s[sidx] << 16);
      r  = rnd[sidx];
      const int nidx = crop_neighbor16(tgt16, sy, sx, sd, nbr);
      v = bittest(vbits, (uint32_t)nidx);
      q = rnd[nidx];
    }

    // partner lanes 2k <-> 2k+1 (same wave; m even, stride 256 even)
    const float psd = __shfl_xor(sd, 1);
    const float pr  = __shfl_xor(r, 1);
    const bool  pv  = (bool)__shfl_xor((int)v, 1);
    const bool pairok = (t < m) && v && pv;

    cont_a += pairok ? fmaxf(fabsf(r - q) - 1e-4f, 0.f) : 0.f;
    if (pairok && ((t & 1u) == 0)) {
      const bool keep = sd >= psd;               // stable argsort(-depth)
      const float ra = keep ? r : pr;
      const float rb = keep ? pr : r;
      rank_a += fmaxf(ra - rb + 1e-4f, 0.f);
      cnt_a  += 1.f;
    }
  }

  // wave reduce -> LDS -> 3 atomics per block
#pragma unroll
  for (int off = 32; off > 0; off >>= 1) {
    rank_a += __shfl_down(rank_a, off);
    cont_a += __shfl_down(cont_a, off);
    cnt_a  += __shfl_down(cnt_a, off);
  }
  if (lane == 0) {
    partial[wave * 3 + 0] = rank_a;
    partial[wave * 3 + 1] = cont_a;
    partial[wave * 3 + 2] = cnt_a;
  }
  __syncthreads();
  if (tid < 3) {
    const float sm = partial[tid] + partial[3 + tid] +
                     partial[6 + tid] + partial[9 + tid];
    atomicAdd(acc + tid, sm);
  }
}

// ---------------- fallback (ws too small): fp32 fused, raw vmask ------------
__device__ __forceinline__ int crop_neighbor32(const float* __restrict__ tgt,
                                               int sy, int sx, float sd,
                                               uint32_t nbr)
{
  float v[7][8];
  const bool interior = (sy >= 3) && (sy <= IMG_H - 4) &&
                        (sx >= 3) && (sx <= IMG_W - 5);
  if (interior) {
    const float* p = tgt + (sy - 3) * IMG_W + (sx - 3);
#pragma unroll
    for (int r = 0; r < 7; r++)
      __builtin_memcpy(&v[r][0], p + r * IMG_W, 32);
  } else {
#pragma unroll
    for (int r = 0; r < 7; r++) {
      const int yy = sy - 3 + r;
      const bool rok = (yy >= 0) && (yy < IMG_H);
#pragma unroll
      for (int c = 0; c < 8; c++) {
        const int xx = sx - 3 + c;
        const bool okc = rok && (c < 7) && (xx >= 0) && (xx < IMG_W);
        v[r][c] = okc ? tgt[yy * IMG_W + xx] : PAD_VAL;
      }
    }
  }
  uint32_t arr[15];
#pragma unroll
  for (int t = 0; t < 15; t++) arr[t] = 0xFFFFFFFFu;
#pragma unroll
  for (int r = 0; r < 7; r++) {
#pragma unroll
    for (int c = 0; c < 7; c++) {
      const int q = r * 7 + c;
      uint32_t key = (__float_as_uint(v[r][c] - sd) & 0x7FFFFFC0u) | (uint32_t)q;
      const int depth = (q + 1 < 15) ? (q + 1) : 15;
#pragma unroll
      for (int t = 0; t < 15; t++) {
        if (t < depth) {
          const uint32_t lo = min(key, arr[t]);
          const uint32_t hi = max(key, arr[t]);
          arr[t] = lo; key = hi;
        }
      }
    }
  }
  uint32_t relkey = 0;
#pragma unroll
  for (int t = 1; t < 15; t++)
    if ((uint32_t)t == nbr) relkey = arr[t];
  const uint32_t rel = relkey & 63u;
  return (sy - 3 + (int)(rel / 7u)) * IMG_W + (sx - 3 + (int)(rel % 7u));
}

__global__ __launch_bounds__(256, 2) void gs_fused(
    const float* __restrict__ tgt,
    const float* __restrict__ rnd,
    const int*   __restrict__ vmask,
    float* __restrict__ acc,
    Keys K)
{
  __shared__ float partial[12];
  const uint32_t tid  = threadIdx.x;
  const uint32_t lane = tid & 63u;
  const uint32_t wave = tid >> 6;
  const uint32_t ui   = blockIdx.x * 256u + tid;

  float rank_c = 0.f, cont_c = 0.f, cnt_c = 0.f;
  if (ui < N_SAMP) {
    const uint32_t syb = jrandint(K, 0, ui, 840u);
    const uint32_t sxb = jrandint(K, 1, ui, 1680u);
    int sy[2], sx[2], sidx[2];
    float sd[2];
    bool sm = true;
#pragma unroll
    for (int j = 0; j < 2; j++) {
      sy[j] = (int)(syb + jrandint(K, 2, 2u * ui + (uint32_t)j, 240u));
      sx[j] = (int)(sxb + jrandint(K, 3, 2u * ui + (uint32_t)j, 240u));
      sidx[j] = sy[j] * IMG_W + sx[j];
      sd[j] = tgt[sidx[j]];
      sm = sm && (vmask[sidx[j]] != 0);
    }
    if (sm) {
      int nidx[2]; bool nm = true;
#pragma unroll
      for (int j = 0; j < 2; j++) {
        const uint32_t nbr = 1u + jrandint(K, 4, 2u * ui + (uint32_t)j, 14u);
        nidx[j] = crop_neighbor32(tgt, sy[j], sx[j], sd[j], nbr);
        nm = nm && (vmask[nidx[j]] != 0);
      }
      if (nm) {
        const float r0 = rnd[sidx[0]], r1 = rnd[sidx[1]];
        const float q0 = rnd[nidx[0]], q1 = rnd[nidx[1]];
        const bool keep = sd[0] >= sd[1];
        const float ra = keep ? r0 : r1;
        const float rb = keep ? r1 : r0;
        rank_c = fmaxf(ra - rb + 1e-4f, 0.f);
        cont_c = fmaxf(fabsf(r0 - q0) - 1e-4f, 0.f)
               + fmaxf(fabsf(r1 - q1) - 1e-4f, 0.f);
        cnt_c = 1.f;
      }
    }
  }
#pragma unroll
  for (int off = 32; off > 0; off >>= 1) {
    rank_c += __shfl_down(rank_c, off);
    cont_c += __shfl_down(cont_c, off);
    cnt_c  += __shfl_down(cnt_c, off);
  }
  if (lane == 0) {
    partial[wave * 3 + 0] = rank_c;
    partial[wave * 3 + 1] = cont_c;
    partial[wave * 3 + 2] = cnt_c;
  }
  __syncthreads();
  if (tid < 3) {
    const float sm2 = partial[tid] + partial[3 + tid] +
                      partial[6 + tid] + partial[9 + tid];
    atomicAdd(acc + tid, sm2);
  }
}

__global__ void gs_finalize(const float* __restrict__ acc, float* __restrict__ out)
{
  const float denom = fmaxf(acc[2], 1.0f);
  out[0] = 0.2f * (acc[0] / denom);                 // WEIGHT * rank_mean
  out[1] = 0.2f * 0.1f * (acc[1] / (denom * 2.0f)); // WEIGHT*CONT_W * cont_mean
}

extern "C" void kernel_launch(void* const* d_in, const int* in_sizes, int n_in,
                              void* d_out, int out_size, void* d_ws, size_t ws_size,
                              hipStream_t stream)
{
  (void)in_sizes; (void)n_in; (void)out_size;
  const float* tgt   = (const float*)d_in[0];
  const float* rnd   = (const float*)d_in[1];
  const int*   vmask = (const int*)d_in[2];
  float* out = (float*)d_out;

  // ws layout (16B-aligned pieces):
  //   [0,16)              acc (3 floats)
  //   [16, +259200)       vbits bit table
  //   [.., +4147200)      tgt16 bf16 table
  //   [.., +8112)         bcount per segment
  //   [.., +4147200)      wlist segmented (SEG * 256 * 8B)
  char* p = (char*)d_ws;
  float*    acc   = (float*)p;
  unsigned long long* vbits = (unsigned long long*)(p + 16);
  uint32_t* tgt16 = (uint32_t*)(p + 16 + 259200);
  uint32_t* bcount = (uint32_t*)(p + 16 + 259200 + 4147200);
  unsigned long long* wlist =
      (unsigned long long*)(p + 16 + 259200 + 4147200 + 8112);
  const size_t need = 16 + 259200 + 4147200 + 8112 + (size_t)SEG * 256 * 8;

  Keys K;
  compute_keys(K);

  hipMemsetAsync(acc, 0, 16, stream);

  if (ws_size >= need) {
    gs_bitpack<<<N_PIX / 256, 256, 0, stream>>>(vmask, vbits);
    gs_pack16<<<(N_PIX / 8 + 255) / 256, 256, 0, stream>>>(tgt, tgt16);
    gs_sample<<<SEG, 256, 0, stream>>>(vbits, bcount, wlist, K);
    gs_crop<<<(SEG + 1) / 2, 256, 0, stream>>>(tgt16, rnd, vbits, bcount,
                                               wlist, acc);
  } else {
    gs_fused<<<N_SAMP / 256, 256, 0, stream>>>(tgt, rnd, vmask, acc, K);
  }
  gs_finalize<<<1, 1, 0, stream>>>(acc, out);
}

// Round 7
// 68.566 us; speedup vs baseline: 1.3169x; 1.3169x over previous
//
#include <hip/hip_runtime.h>
#include <stdint.h>

// ---------------------------------------------------------------------------
// GSDepthRankingLoss on MI355X — R6:
//   - padded bf16 crop table (1936x1088, border=bf16(-1e6)): no edge paths
//   - gs_crop: ONE asm block = 7x global_load_dwordx4 + s_waitcnt vmcnt(0)
//     (guaranteed batched gather; one latency exposure per crop)
//   - no unpack array (R5's 57MB scratch spill eliminated): bf16 cells
//     extracted from packed words with static indices + cndmask on parity
//   - center depth taken from crop row 3 (one less gather)
// JAX threefry (partitionable) verified bit-exact R0-R5.
// ---------------------------------------------------------------------------

#define IMG_W 1920
#define IMG_H 1080
#define N_PIX (IMG_W * IMG_H)
#define N_SAMP 518400          // int(1920*1080*0.25) == 2025 * 256
#define SEG    2025            // worklist segments (one per sample block)
#define PAD_VAL (-1000000.0f)
#define PW 968                 // padded table words per row (1936 px / 2)
#define PH 1088                // padded table rows
#define PAD16 0xC974u          // bf16(-1e6) = -999424.0f

typedef uint32_t u32x4 __attribute__((ext_vector_type(4)));

struct Keys { uint32_t k[5][2][2]; };  // [randint id][k1|k2][key word]

// Threefry-2x32, 20 rounds (Random123 / JAX-compatible).
static __host__ __device__ inline void tf2x32(uint32_t k0, uint32_t k1,
                                              uint32_t x0, uint32_t x1,
                                              uint32_t& o0, uint32_t& o1)
{
  const uint32_t ks2 = k0 ^ k1 ^ 0x1BD11BDAu;
  x0 += k0; x1 += k1;
#define TFR(r) { x0 += x1; x1 = (x1 << (r)) | (x1 >> (32 - (r))); x1 ^= x0; }
  TFR(13) TFR(15) TFR(26) TFR(6)
  x0 += k1;  x1 += ks2 + 1u;
  TFR(17) TFR(29) TFR(16) TFR(24)
  x0 += ks2; x1 += k0 + 2u;
  TFR(13) TFR(15) TFR(26) TFR(6)
  x0 += k0;  x1 += k1 + 3u;
  TFR(17) TFR(29) TFR(16) TFR(24)
  x0 += k1;  x1 += ks2 + 4u;
  TFR(13) TFR(15) TFR(26) TFR(6)
  x0 += ks2; x1 += k0 + 5u;
#undef TFR
  o0 = x0; o1 = x1;
}

__device__ __forceinline__ uint32_t jrbits(const uint32_t kk[2], uint32_t f)
{
  uint32_t a, b;
  tf2x32(kk[0], kk[1], 0u, f, a, b);   // partitionable: counts = (0, f)
  return a ^ b;                        // 32-bit fold
}

__device__ __forceinline__ uint32_t jrandint(const Keys& K, int r, uint32_t f,
                                             uint32_t span)
{
  const uint32_t hi = jrbits(K.k[r][0], f);
  const uint32_t lo = jrbits(K.k[r][1], f);
  uint32_t m = 65536u % span;
  m = (m * m) % span;
  return ((hi % span) * m + (lo % span)) % span;
}

static void compute_keys(Keys& K)
{
  uint32_t ks[5][2];
  for (uint32_t t = 0; t < 5; t++) {
    uint32_t a, b; tf2x32(0u, 42u, 0u, t, a, b);   // split of key(42)
    ks[t][0] = a; ks[t][1] = b;
  }
  for (int r = 0; r < 5; r++) {                    // randint's internal _split
    uint32_t a, b;
    tf2x32(ks[r][0], ks[r][1], 0u, 0u, a, b); K.k[r][0][0] = a; K.k[r][0][1] = b;
    tf2x32(ks[r][0], ks[r][1], 0u, 1u, a, b); K.k[r][1][0] = a; K.k[r][1][1] = b;
  }
}

__device__ __forceinline__ bool bittest(const unsigned long long* __restrict__ vb,
                                        uint32_t idx)
{
  return ((vb[idx >> 6] >> (idx & 63u)) & 1ull) != 0ull;
}

// ---------------- K1: bitpack valid mask (2073600 ints -> 259KB) ------------
__global__ __launch_bounds__(256) void gs_bitpack(
    const int* __restrict__ vmask,
    unsigned long long* __restrict__ vbits)
{
  const uint32_t gid = blockIdx.x * 256u + threadIdx.x;   // 8100*256 == N_PIX
  const unsigned long long ball = __ballot(vmask[gid] != 0);
  if ((threadIdx.x & 63u) == 0) vbits[gid >> 6] = ball;
}

// ---------------- K1b: padded bf16 table of target depths -------------------
// word w = (row wy, cols 2wx,2wx+1) of padded image; src px = padded - 4.
__global__ __launch_bounds__(256) void gs_pack16(
    const float* __restrict__ tgt,
    uint32_t* __restrict__ t16p)
{
  const uint32_t w = blockIdx.x * 256u + threadIdx.x;
  if (w >= (uint32_t)(PW * PH)) return;
  const uint32_t wy = w / PW, wx = w % PW;
  const int sy  = (int)wy - 4;
  const int sx0 = 2 * (int)wx - 4;
  uint32_t lo = PAD16, hi = PAD16;
  if (sy >= 0 && sy < IMG_H) {
    const uint32_t* src = (const uint32_t*)tgt + (size_t)sy * IMG_W;
    if (sx0     >= 0 && sx0     < IMG_W) lo = src[sx0] >> 16;
    if (sx0 + 1 >= 0 && sx0 + 1 < IMG_W) hi = src[sx0 + 1] >> 16;
  }
  t16p[w] = lo | (hi << 16);
}

// ---------------- K2: PRNG + mask -> segmented worklist (NO atomics) --------
// Entry (64b): [nbr1:4 @48][nbr0:4 @44][sy0:11 @33][sx0:11 @22][sy1:11 @11][sx1:11 @0]
__global__ __launch_bounds__(256) void gs_sample(
    const unsigned long long* __restrict__ vbits,
    uint32_t* __restrict__ bcount,
    unsigned long long* __restrict__ wlist,
    Keys K)
{
  __shared__ unsigned long long ent[256];
  __shared__ uint32_t scnt[4];

  const uint32_t tid  = threadIdx.x;
  const uint32_t lane = tid & 63u;
  const uint32_t wave = tid >> 6;
  const uint32_t ui   = blockIdx.x * 256u + tid;   // grid covers N_SAMP exactly

  // 8 independent randint chains; fence encourages simultaneous liveness.
  const uint32_t syb  = jrandint(K, 0, ui, 840u);    // H - 240
  const uint32_t sxb  = jrandint(K, 1, ui, 1680u);   // W - 240
  const uint32_t oy0  = jrandint(K, 2, 2u * ui,      240u);
  const uint32_t oy1  = jrandint(K, 2, 2u * ui + 1u, 240u);
  const uint32_t ox0  = jrandint(K, 3, 2u * ui,      240u);
  const uint32_t ox1  = jrandint(K, 3, 2u * ui + 1u, 240u);
  const uint32_t nb0  = jrandint(K, 4, 2u * ui,      14u);
  const uint32_t nb1  = jrandint(K, 4, 2u * ui + 1u, 14u);
  asm volatile("" :: "v"(syb), "v"(sxb), "v"(oy0), "v"(oy1),
                     "v"(ox0), "v"(ox1), "v"(nb0), "v"(nb1));

  const uint32_t sy0 = syb + oy0, sy1 = syb + oy1;
  const uint32_t sx0 = sxb + ox0, sx1 = sxb + ox1;
  const bool ok = bittest(vbits, sy0 * IMG_W + sx0) &&
                  bittest(vbits, sy1 * IMG_W + sx1);

  const unsigned long long ball = __ballot(ok);
  if (lane == 0) scnt[wave] = (uint32_t)__popcll(ball);
  __syncthreads();

  uint32_t base = 0;
#pragma unroll
  for (uint32_t w = 0; w < 4; w++) if (w < wave) base += scnt[w];
  const uint32_t nsurv = scnt[0] + scnt[1] + scnt[2] + scnt[3];

  if (ok) {
    const uint32_t pos = base + (uint32_t)__popcll(ball & ((1ull << lane) - 1ull));
    ent[pos] = ((unsigned long long)(1u + nb1) << 48) |
               ((unsigned long long)(1u + nb0) << 44) |
               ((unsigned long long)sy0 << 33) | ((unsigned long long)sx0 << 22) |
               ((unsigned long long)sy1 << 11) |  (unsigned long long)sx1;
  }
  if (tid == 0) bcount[blockIdx.x] = nsurv;
  __syncthreads();

  unsigned long long* wb = wlist + (size_t)blockIdx.x * 256u;
  for (uint32_t t = tid; t < nsurv; t += 256u)
    wb[t] = ent[t];                      // coalesced, segment-local
}

// nbr-th nearest neighbour from the PADDED bf16 table. One asm block issues
// all 7 row loads then waits once; cells extracted with static word indices.
// Also returns the (bf16) center depth via sd_out — no separate gather.
__device__ __forceinline__ int crop_neighbor16(
    const uint32_t* __restrict__ t16p, int sy, int sx,
    float& sd_out, uint32_t nbr)
{
  const int prow0 = sy + 1;              // (sy-3) + 4 pad
  const int pcol  = sx + 1;              // (sx-3) + 4 pad
  const int ex    = pcol & ~1;           // even px base
  const uint32_t s = (uint32_t)(pcol & 1);
  const uint32_t* p = t16p + (size_t)prow0 * PW + (ex >> 1);

  u32x4 R0, R1, R2, R3, R4, R5, R6;
  asm volatile(
      "global_load_dwordx4 %0, %7, off\n\t"
      "global_load_dwordx4 %1, %8, off\n\t"
      "global_load_dwordx4 %2, %9, off\n\t"
      "global_load_dwordx4 %3, %10, off\n\t"
      "global_load_dwordx4 %4, %11, off\n\t"
      "global_load_dwordx4 %5, %12, off\n\t"
      "global_load_dwordx4 %6, %13, off\n\t"
      "s_waitcnt vmcnt(0)"
      : "=&v"(R0), "=&v"(R1), "=&v"(R2), "=&v"(R3),
        "=&v"(R4), "=&v"(R5), "=&v"(R6)
      : "v"(p), "v"(p + PW), "v"(p + 2 * PW), "v"(p + 3 * PW),
        "v"(p + 4 * PW), "v"(p + 5 * PW), "v"(p + 6 * PW));

  // center = crop row 3, col 3 -> halfword k = s+3
  const uint32_t sdbits = s ? (R3[2] << 16) : (R3[1] & 0xFFFF0000u);
  const float sd = __uint_as_float(sdbits);
  sd_out = sd;

  const u32x4 R[7] = { R0, R1, R2, R3, R4, R5, R6 };

  // 15 smallest of 49 keys: (|v-sd|bits & ~63) | pos; stable ties by pos.
  uint32_t arr[15];
#pragma unroll
  for (int t = 0; t < 15; t++) arr[t] = 0xFFFFFFFFu;

#pragma unroll
  for (int r = 0; r < 7; r++) {
    const u32x4 W = R[r];
#pragma unroll
    for (int c = 0; c < 7; c++) {
      // halfword k = c + s of the 8 loaded; static words, cndmask on s.
      uint32_t bits;
      if (c & 1) bits = s ? (W[(c + 1) >> 1] << 16) : (W[c >> 1] & 0xFFFF0000u);
      else       bits = s ? (W[c >> 1] & 0xFFFF0000u) : (W[c >> 1] << 16);
      const float v = __uint_as_float(bits);
      const int q = r * 7 + c;
      uint32_t key = (__float_as_uint(v - sd) & 0x7FFFFFC0u) | (uint32_t)q;
      const int depth = (q + 1 < 15) ? (q + 1) : 15;     // triangular insert
#pragma unroll
      for (int t = 0; t < 15; t++) {
        if (t < depth) {
          const uint32_t lo = min(key, arr[t]);
          const uint32_t hi = max(key, arr[t]);
          arr[t] = lo; key = hi;
        }
      }
    }
  }

  uint32_t relkey = 0;
#pragma unroll
  for (int t = 1; t < 15; t++)
    if ((uint32_t)t == nbr) relkey = arr[t];
  const uint32_t rel = relkey & 63u;
  return (sy - 3 + (int)(rel / 7u)) * IMG_W + (sx - 3 + (int)(rel % 7u));
}

// ---------------- K3: crops on segment pairs --------------------------------
__global__ __launch_bounds__(256, 4) void gs_crop(
    const uint32_t* __restrict__ t16p,
    const float* __restrict__ rnd,
    const unsigned long long* __restrict__ vbits,
    const uint32_t* __restrict__ bcount,
    const unsigned long long* __restrict__ wlist,
    float* __restrict__ acc)
{
  __shared__ float partial[12];
  const uint32_t tid  = threadIdx.x;
  const uint32_t lane = tid & 63u;
  const uint32_t wave = tid >> 6;

  const uint32_t seg0 = 2u * blockIdx.x;
  const uint32_t c0 = bcount[seg0];
  const uint32_t c1 = (seg0 + 1 < SEG) ? bcount[seg0 + 1] : 0;
  const uint32_t m  = 2u * (c0 + c1);            // crops this block (even)

  float rank_a = 0.f, cont_a = 0.f, cnt_a = 0.f;
  for (uint32_t t = tid; t < ((m + 255u) & ~255u); t += 256u) {
    float sd = 0.f, r = 0.f, q = 0.f;
    bool v = false;
    if (t < m) {
      const uint32_t tc0 = 2u * c0;
      const unsigned long long e = (t < tc0)
          ? wlist[(size_t)seg0 * 256u + (t >> 1)]
          : wlist[(size_t)(seg0 + 1) * 256u + ((t - tc0) >> 1)];
      const int j = (int)(t & 1u);               // tc0 even -> parity safe
      const int sy  = j ? (int)((e >> 11) & 2047u) : (int)((e >> 33) & 2047u);
      const int sx  = j ? (int)( e        & 2047u) : (int)((e >> 22) & 2047u);
      const uint32_t nbr = j ? (uint32_t)((e >> 48) & 15u)
                             : (uint32_t)((e >> 44) & 15u);
      r = rnd[sy * IMG_W + sx];                  // prefetched; drained by
      const int nidx = crop_neighbor16(t16p, sy, sx, sd, nbr);  // asm vmcnt(0)
      v = bittest(vbits, (uint32_t)nidx);
      q = rnd[nidx];
    }

    // partner lanes 2k <-> 2k+1 (same wave; m even, stride 256 even)
    const float psd = __shfl_xor(sd, 1);
    const float pr  = __shfl_xor(r, 1);
    const bool  pv  = (bool)__shfl_xor((int)v, 1);
    const bool pairok = (t < m) && v && pv;

    cont_a += pairok ? fmaxf(fabsf(r - q) - 1e-4f, 0.f) : 0.f;
    if (pairok && ((t & 1u) == 0)) {
      const bool keep = sd >= psd;               // stable argsort(-depth)
      const float ra = keep ? r : pr;
      const float rb = keep ? pr : r;
      rank_a += fmaxf(ra - rb + 1e-4f, 0.f);
      cnt_a  += 1.f;
    }
  }

  // wave reduce -> LDS -> 3 atomics per block
#pragma unroll
  for (int off = 32; off > 0; off >>= 1) {
    rank_a += __shfl_down(rank_a, off);
    cont_a += __shfl_down(cont_a, off);
    cnt_a  += __shfl_down(cnt_a, off);
  }
  if (lane == 0) {
    partial[wave * 3 + 0] = rank_a;
    partial[wave * 3 + 1] = cont_a;
    partial[wave * 3 + 2] = cnt_a;
  }
  __syncthreads();
  if (tid < 3) {
    const float sm = partial[tid] + partial[3 + tid] +
                     partial[6 + tid] + partial[9 + tid];
    atomicAdd(acc + tid, sm);
  }
}

// ---------------- fallback (ws too small): fp32 fused, raw vmask ------------
__device__ __forceinline__ int crop_neighbor32(const float* __restrict__ tgt,
                                               int sy, int sx, float sd,
                                               uint32_t nbr)
{
  float v[7][8];
  const bool interior = (sy >= 3) && (sy <= IMG_H - 4) &&
                        (sx >= 3) && (sx <= IMG_W - 5);
  if (interior) {
    const float* p = tgt + (sy - 3) * IMG_W + (sx - 3);
#pragma unroll
    for (int r = 0; r < 7; r++)
      __builtin_memcpy(&v[r][0], p + r * IMG_W, 32);
  } else {
#pragma unroll
    for (int r = 0; r < 7; r++) {
      const int yy = sy - 3 + r;
      const bool rok = (yy >= 0) && (yy < IMG_H);
#pragma unroll
      for (int c = 0; c < 8; c++) {
        const int xx = sx - 3 + c;
        const bool okc = rok && (c < 7) && (xx >= 0) && (xx < IMG_W);
        v[r][c] = okc ? tgt[yy * IMG_W + xx] : PAD_VAL;
      }
    }
  }
  uint32_t arr[15];
#pragma unroll
  for (int t = 0; t < 15; t++) arr[t] = 0xFFFFFFFFu;
#pragma unroll
  for (int r = 0; r < 7; r++) {
#pragma unroll
    for (int c = 0; c < 7; c++) {
      const int q = r * 7 + c;
      uint32_t key = (__float_as_uint(v[r][c] - sd) & 0x7FFFFFC0u) | (uint32_t)q;
      const int depth = (q + 1 < 15) ? (q + 1) : 15;
#pragma unroll
      for (int t = 0; t < 15; t++) {
        if (t < depth) {
          const uint32_t lo = min(key, arr[t]);
          const uint32_t hi = max(key, arr[t]);
          arr[t] = lo; key = hi;
        }
      }
    }
  }
  uint32_t relkey = 0;
#pragma unroll
  for (int t = 1; t < 15; t++)
    if ((uint32_t)t == nbr) relkey = arr[t];
  const uint32_t rel = relkey & 63u;
  return (sy - 3 + (int)(rel / 7u)) * IMG_W + (sx - 3 + (int)(rel % 7u));
}

__global__ __launch_bounds__(256, 2) void gs_fused(
    const float* __restrict__ tgt,
    const float* __restrict__ rnd,
    const int*   __restrict__ vmask,
    float* __restrict__ acc,
    Keys K)
{
  __shared__ float partial[12];
  const uint32_t tid  = threadIdx.x;
  const uint32_t lane = tid & 63u;
  const uint32_t wave = tid >> 6;
  const uint32_t ui   = blockIdx.x * 256u + tid;

  float rank_c = 0.f, cont_c = 0.f, cnt_c = 0.f;
  if (ui < N_SAMP) {
    const uint32_t syb = jrandint(K, 0, ui, 840u);
    const uint32_t sxb = jrandint(K, 1, ui, 1680u);
    int sy[2], sx[2], sidx[2];
    float sd[2];
    bool sm = true;
#pragma unroll
    for (int j = 0; j < 2; j++) {
      sy[j] = (int)(syb + jrandint(K, 2, 2u * ui + (uint32_t)j, 240u));
      sx[j] = (int)(sxb + jrandint(K, 3, 2u * ui + (uint32_t)j, 240u));
      sidx[j] = sy[j] * IMG_W + sx[j];
      sd[j] = tgt[sidx[j]];
      sm = sm && (vmask[sidx[j]] != 0);
    }
    if (sm) {
      int nidx[2]; bool nm = true;
#pragma unroll
      for (int j = 0; j < 2; j++) {
        const uint32_t nbr = 1u + jrandint(K, 4, 2u * ui + (uint32_t)j, 14u);
        nidx[j] = crop_neighbor32(tgt, sy[j], sx[j], sd[j], nbr);
        nm = nm && (vmask[nidx[j]] != 0);
      }
      if (nm) {
        const float r0 = rnd[sidx[0]], r1 = rnd[sidx[1]];
        const float q0 = rnd[nidx[0]], q1 = rnd[nidx[1]];
        const bool keep = sd[0] >= sd[1];
        const float ra = keep ? r0 : r1;
        const float rb = keep ? r1 : r0;
        rank_c = fmaxf(ra - rb + 1e-4f, 0.f);
        cont_c = fmaxf(fabsf(r0 - q0) - 1e-4f, 0.f)
               + fmaxf(fabsf(r1 - q1) - 1e-4f, 0.f);
        cnt_c = 1.f;
      }
    }
  }
#pragma unroll
  for (int off = 32; off > 0; off >>= 1) {
    rank_c += __shfl_down(rank_c, off);
    cont_c += __shfl_down(cont_c, off);
    cnt_c  += __shfl_down(cnt_c, off);
  }
  if (lane == 0) {
    partial[wave * 3 + 0] = rank_c;
    partial[wave * 3 + 1] = cont_c;
    partial[wave * 3 + 2] = cnt_c;
  }
  __syncthreads();
  if (tid < 3) {
    const float sm2 = partial[tid] + partial[3 + tid] +
                      partial[6 + tid] + partial[9 + tid];
    atomicAdd(acc + tid, sm2);
  }
}

__global__ void gs_finalize(const float* __restrict__ acc, float* __restrict__ out)
{
  const float denom = fmaxf(acc[2], 1.0f);
  out[0] = 0.2f * (acc[0] / denom);                 // WEIGHT * rank_mean
  out[1] = 0.2f * 0.1f * (acc[1] / (denom * 2.0f)); // WEIGHT*CONT_W * cont_mean
}

extern "C" void kernel_launch(void* const* d_in, const int* in_sizes, int n_in,
                              void* d_out, int out_size, void* d_ws, size_t ws_size,
                              hipStream_t stream)
{
  (void)in_sizes; (void)n_in; (void)out_size;
  const float* tgt   = (const float*)d_in[0];
  const float* rnd   = (const float*)d_in[1];
  const int*   vmask = (const int*)d_in[2];
  float* out = (float*)d_out;

  // ws layout (all 16B-aligned):
  //   [0,16)        acc (3 floats)
  //   +259200       vbits bit table
  //   +4213504      t16p padded bf16 table (968w x 1088r x 4B)
  //   +8112         bcount per segment (2025*4, padded to 16)
  //   +4147200      wlist segmented (SEG * 256 * 8B)
  char* p = (char*)d_ws;
  float*    acc   = (float*)p;
  unsigned long long* vbits = (unsigned long long*)(p + 16);
  uint32_t* t16p  = (uint32_t*)(p + 16 + 259200);
  uint32_t* bcount = (uint32_t*)(p + 16 + 259200 + 4213504);
  unsigned long long* wlist =
      (unsigned long long*)(p + 16 + 259200 + 4213504 + 8112);
  const size_t need = 16 + 259200 + 4213504 + 8112 + (size_t)SEG * 256 * 8;

  Keys K;
  compute_keys(K);

  hipMemsetAsync(acc, 0, 16, stream);

  if (ws_size >= need) {
    gs_bitpack<<<N_PIX / 256, 256, 0, stream>>>(vmask, vbits);
    gs_pack16<<<(PW * PH + 255) / 256, 256, 0, stream>>>(tgt, t16p);
    gs_sample<<<SEG, 256, 0, stream>>>(vbits, bcount, wlist, K);
    gs_crop<<<(SEG + 1) / 2, 256, 0, stream>>>(t16p, rnd, vbits, bcount,
                                               wlist, acc);
  } else {
    gs_fused<<<N_SAMP / 256, 256, 0, stream>>>(tgt, rnd, vmask, acc, K);
  }
  gs_finalize<<<1, 1, 0, stream>>>(acc, out);
}